// Round 2
// baseline (483.685 us; speedup 1.0000x reference)
//
#include <hip/hip_runtime.h>
#include <hip/hip_bf16.h>

typedef __bf16 bf16x8 __attribute__((ext_vector_type(8)));
typedef float  floatx4 __attribute__((ext_vector_type(4)));

constexpr int B_SZ  = 1024;
constexpr int NB    = 1024;
constexpr int DIN   = 64;
constexpr int DOUT  = 64;
constexpr int M_TILE = 128;        // batch rows per WG iteration
constexpr int ITERS  = 4;          // m-tiles per workgroup
constexpr int LDS_STRIDE = 72;     // bf16 elems per W row (pad 64 -> 72, 16B aligned)

__global__ __launch_bounds__(256)
void block_linear_kernel(const float* __restrict__ x,
                         const float* __restrict__ W,
                         const float* __restrict__ bias,
                         float* __restrict__ out)
{
    __shared__ __bf16 sW[DOUT * LDS_STRIDE];   // 9216 B

    const int bid  = blockIdx.x;               // [0, 2048)
    const int n    = bid >> 1;                 // block index
    const int half = bid & 1;                  // which group of 4 m-tiles
    const int tid  = threadIdx.x;
    const int wave = tid >> 6;
    const int lane = tid & 63;
    const int r    = lane & 15;                // A-row / B-col / D-col
    const int q    = lane >> 4;                // quad

    // ---- issue W[n] global loads first (64x64 fp32 = 16 KB, coalesced f4) ----
    const float4* Wf4 = reinterpret_cast<const float4*>(W + (size_t)n * DOUT * DIN);
    float4 wreg[4];
    #pragma unroll
    for (int i = 0; i < 4; ++i) wreg[i] = Wf4[i * 256 + tid];

    // ---- A prefetch buffer + loader: [mtile][ks][h] f4 pairs ----
    float4 buf[2][2][2];
    auto loadA = [&](int it) {
        const int m0 = (half * ITERS + it) * M_TILE + wave * 32;
        #pragma unroll
        for (int mtile = 0; mtile < 2; ++mtile) {
            #pragma unroll
            for (int ks = 0; ks < 2; ++ks) {
                const float* p = x + ((size_t)(m0 + mtile * 16 + r) * NB + n) * DIN
                                   + ks * 32 + q * 8;
                buf[mtile][ks][0] = *reinterpret_cast<const float4*>(p);
                buf[mtile][ks][1] = *reinterpret_cast<const float4*>(p + 4);
            }
        }
    };
    loadA(0);                                   // iter-0 A loads in flight

    // ---- bias for this WG's 4 o-columns (per lane) ----
    float bv[4];
    #pragma unroll
    for (int ot = 0; ot < 4; ++ot) bv[ot] = bias[n * DOUT + ot * 16 + r];

    // ---- W -> LDS (bf16, padded stride) ----
    #pragma unroll
    for (int i = 0; i < 4; ++i) {
        const int e  = i * 256 + tid;           // float4 index in 64x64 tile
        const int o  = e >> 4;
        const int k0 = (e & 15) << 2;
        union { __bf16 h[4]; ushort4 u; } pk;
        pk.h[0] = (__bf16)wreg[i].x; pk.h[1] = (__bf16)wreg[i].y;
        pk.h[2] = (__bf16)wreg[i].z; pk.h[3] = (__bf16)wreg[i].w;
        *reinterpret_cast<ushort4*>(&sW[o * LDS_STRIDE + k0]) = pk.u;
    }
    __syncthreads();

    // ---- B fragments, resident in registers for the whole loop ----
    // B[col = lane&15][k = quad*8 + j] = W[o][k]
    bf16x8 bfrag[4][2];
    #pragma unroll
    for (int ot = 0; ot < 4; ++ot) {
        #pragma unroll
        for (int ks = 0; ks < 2; ++ks) {
            const int o = ot * 16 + r;
            bfrag[ot][ks] = *reinterpret_cast<const bf16x8*>(
                &sW[o * LDS_STRIDE + ks * 32 + q * 8]);
        }
    }

    // ---- pipelined main loop over 4 m-tiles ----
    #pragma unroll
    for (int it = 0; it < ITERS; ++it) {
        const int m0 = (half * ITERS + it) * M_TILE + wave * 32;

        // convert current A buffer -> bf16 fragments (waits on its loads)
        bf16x8 afrag[2][2];
        #pragma unroll
        for (int mtile = 0; mtile < 2; ++mtile) {
            #pragma unroll
            for (int ks = 0; ks < 2; ++ks) {
                const float4 f0 = buf[mtile][ks][0];
                const float4 f1 = buf[mtile][ks][1];
                bf16x8 a;
                a[0] = (__bf16)f0.x; a[1] = (__bf16)f0.y;
                a[2] = (__bf16)f0.z; a[3] = (__bf16)f0.w;
                a[4] = (__bf16)f1.x; a[5] = (__bf16)f1.y;
                a[6] = (__bf16)f1.z; a[7] = (__bf16)f1.w;
                afrag[mtile][ks] = a;
            }
        }

        // issue next iteration's A loads (overlap with MFMA + stores below)
        if (it + 1 < ITERS) loadA(it + 1);

        // MFMA: 2 m-subtiles x 4 o-tiles x 2 K-steps
        floatx4 acc[2][4];
        #pragma unroll
        for (int mtile = 0; mtile < 2; ++mtile)
            #pragma unroll
            for (int ot = 0; ot < 4; ++ot)
                acc[mtile][ot] = (floatx4){0.f, 0.f, 0.f, 0.f};

        #pragma unroll
        for (int mtile = 0; mtile < 2; ++mtile)
            #pragma unroll
            for (int ot = 0; ot < 4; ++ot)
                #pragma unroll
                for (int ks = 0; ks < 2; ++ks)
                    acc[mtile][ot] = __builtin_amdgcn_mfma_f32_16x16x32_bf16(
                        afrag[mtile][ks], bfrag[ot][ks], acc[mtile][ot], 0, 0, 0);

        // epilogue: + bias, store. D: col = lane&15, row = quad*4 + reg
        #pragma unroll
        for (int ot = 0; ot < 4; ++ot)
            #pragma unroll
            for (int mtile = 0; mtile < 2; ++mtile)
                #pragma unroll
                for (int reg = 0; reg < 4; ++reg) {
                    const int row = m0 + mtile * 16 + q * 4 + reg;
                    out[((size_t)row * NB + n) * DOUT + ot * 16 + r]
                        = acc[mtile][ot][reg] + bv[ot];
                }
    }
}

extern "C" void kernel_launch(void* const* d_in, const int* in_sizes, int n_in,
                              void* d_out, int out_size, void* d_ws, size_t ws_size,
                              hipStream_t stream) {
    const float* x  = (const float*)d_in[0];
    const float* W  = (const float*)d_in[1];
    const float* b  = (const float*)d_in[2];
    float* out      = (float*)d_out;

    dim3 grid(NB * (B_SZ / (M_TILE * ITERS)));   // 1024 * 2 = 2048
    dim3 block(256);
    hipLaunchKernelGGL(block_linear_kernel, grid, block, 0, stream, x, W, b, out);
}